// Round 3
// baseline (114.185 us; speedup 1.0000x reference)
//
#include <hip/hip_runtime.h>
#include <hip/hip_bf16.h>

__device__ __forceinline__ float sigm(float x) { return 1.0f / (1.0f + __expf(-x)); }

// Fully fused FRAP forward, float32 I/O. One thread per output element (b', i).
// x[b,l,:] depends only on (phase_bit, veh_count) in {0,1}x{0..29} = 60 combos.
// LDS tables: YA[60][20] = w_feat[:, :16].X[key] (+b_feat/4), YB likewise for
// w_feat[:, 16:]; WCM[m][q][o] = w_comb[q,o] * relu(w_const[o,:].emb_const[m,:]+b_const[o]).
// Output (b',i) = sum_{j=0..6} relu(w_final . relu(WCM[m_ij] . xf + b_comb) + b_final)
// where xf = relu(YA[kA0]+YA[kA1]+YB[kB0]+YB[kB1]) from source batch b = g%B,
// pair p = g/B, g = 56 b' + 7 i + j (the transpose-reshape scramble).
__global__ __launch_bounds__(256) void frap_fused(
    const float* __restrict__ feat,      // B*16
    const float* __restrict__ emb_phase, // 8
    const float* __restrict__ w_veh,     // 4
    const float* __restrict__ b_veh,     // 4
    const float* __restrict__ w_line,    // 128
    const float* __restrict__ b_line,    // 16
    const float* __restrict__ emb_const, // 8
    const float* __restrict__ w_feat,    // 640
    const float* __restrict__ b_feat,    // 20
    const float* __restrict__ w_const,   // 80
    const float* __restrict__ b_const,   // 20
    const float* __restrict__ w_comb,    // 400
    const float* __restrict__ b_comb,    // 20
    const float* __restrict__ w_final,   // 20
    const float* __restrict__ b_final,   // 1
    const int*  __restrict__ cmask,      // 56
    float* __restrict__ out,             // B*8
    int B)
{
    __shared__ __align__(16) float s_ya[60 * 20];
    __shared__ __align__(16) float s_yb[60 * 20];
    __shared__ __align__(16) float s_wcm[2 * 20 * 20];
    __shared__ float s_stage[820];   // [0,128)=w_line [128,768)=w_feat [768,784)=b_line
                                     // [784,788)=w_veh [788,792)=b_veh [792,800)=emb_phase [800,820)=b_feat
    __shared__ float s_bcomb[20], s_wfin[20];
    __shared__ unsigned s_maskbits[8];
    __shared__ float s_bfin;

    const int tid = threadIdx.x;

    for (int k = tid; k < 128; k += 256) s_stage[k] = w_line[k];
    for (int k = tid; k < 640; k += 256) s_stage[128 + k] = w_feat[k];
    if (tid < 16)                s_stage[768 + tid] = b_line[tid];
    if (tid < 4)                 s_stage[784 + tid] = w_veh[tid];
    if (tid >= 4 && tid < 8)     s_stage[784 + tid] = b_veh[tid - 4];
    if (tid >= 8 && tid < 16)    s_stage[784 + tid] = emb_phase[tid - 8];
    if (tid >= 16 && tid < 36)   s_stage[784 + tid] = b_feat[tid - 16];
    __syncthreads();

    // ---- build YA/YB tables (60 keys = veh*2 + phase_bit) ----
    if (tid < 60) {
        int veh = tid >> 1, pb = tid & 1;
        float vf = (float)veh;
        float line[8];
#pragma unroll
        for (int k = 0; k < 4; k++) line[k] = sigm(fmaf(vf, s_stage[784 + k], s_stage[788 + k]));
#pragma unroll
        for (int k = 0; k < 4; k++) line[4 + k] = sigm(s_stage[792 + pb * 4 + k]);
        float X[16];
#pragma unroll
        for (int o = 0; o < 16; o++) {
            float x = s_stage[768 + o];
#pragma unroll
            for (int d = 0; d < 8; d++) x = fmaf(line[d], s_stage[o * 8 + d], x);
            X[o] = fmaxf(x, 0.f);
        }
#pragma unroll
        for (int o = 0; o < 20; o++) {
            float a = 0.25f * s_stage[800 + o];
            float bb = a;
#pragma unroll
            for (int c = 0; c < 16; c++) {
                a  = fmaf(X[c], s_stage[128 + o * 32 + c], a);
                bb = fmaf(X[c], s_stage[128 + o * 32 + 16 + c], bb);
            }
            s_ya[tid * 20 + o] = a;
            s_yb[tid * 20 + o] = bb;
        }
    }

    // ---- build WCM (w_comb with relu(yc) folded) ----
    for (int idx = tid; idx < 800; idx += 256) {
        int m = idx / 400;
        int r = idx - m * 400;
        int q = r / 20;
        int o = r - q * 20;
        float yc = b_const[o];
#pragma unroll
        for (int k = 0; k < 4; k++)
            yc = fmaf(w_const[o * 4 + k], emb_const[m * 4 + k], yc);
        s_wcm[idx] = w_comb[q * 20 + o] * fmaxf(yc, 0.f);
    }
    if (tid < 20) { s_bcomb[tid] = b_comb[tid]; s_wfin[tid] = w_final[tid]; }
    if (tid < 8) {
        unsigned mb = 0;
        for (int j = 0; j < 7; j++) mb |= ((unsigned)cmask[tid * 7 + j] & 1u) << j;
        s_maskbits[tid] = mb;
    }
    if (tid == 0) s_bfin = b_final[0];
    __syncthreads();

    // ---- main: one thread per (b', i) ----
    int t = blockIdx.x * 256 + tid;
    if (t >= B * 8) return;
    int bp = t >> 3, i = t & 7;
    unsigned mrow = s_maskbits[i];
    unsigned g = (unsigned)bp * 56u + (unsigned)i * 7u;   // = 7*t + i? no: = 7t when i folded; g = 7*t? bp*56+i*7 = 7*(bp*8+i) = 7*t
    unsigned p = g / (unsigned)B;     // source pair index (0..55)
    unsigned b = g - p * (unsigned)B; // source batch index

    const unsigned L0T = 0x64204051u, L1T = 0x75316273u; // PHASE_LANES nibble tables
    unsigned pi = p / 7u;
    unsigned c7 = p - pi * 7u;
    unsigned pj = c7 + (c7 >= pi ? 1u : 0u);
    int la0 = (L0T >> (pi * 4)) & 15, la1 = (L1T >> (pi * 4)) & 15;
    int lb0 = (L0T >> (pj * 4)) & 15, lb1 = (L1T >> (pj * 4)) & 15;

    float total = 0.f;
    for (int j = 0; j < 7; j++) {
        if (b >= (unsigned)B) {   // wrap into next pair (rare)
            b -= (unsigned)B;
            p++;
            pi = p / 7u;
            c7 = p - pi * 7u;
            pj = c7 + (c7 >= pi ? 1u : 0u);
            la0 = (L0T >> (pi * 4)) & 15; la1 = (L1T >> (pi * 4)) & 15;
            lb0 = (L0T >> (pj * 4)) & 15; lb1 = (L1T >> (pj * 4)) & 15;
        }
        const float* row = feat + (size_t)b * 16;
        float bA0 = row[la0], vA0 = row[8 + la0];
        float bA1 = row[la1], vA1 = row[8 + la1];
        float bB0 = row[lb0], vB0 = row[8 + lb0];
        float bB1 = row[lb1], vB1 = row[8 + lb1];
        int kA0 = (int)fmaf(vA0, 2.f, bA0);
        int kA1 = (int)fmaf(vA1, 2.f, bA1);
        int kB0 = (int)fmaf(vB0, 2.f, bB0);
        int kB1 = (int)fmaf(vB1, 2.f, bB1);
        kA0 = min(59, max(0, kA0)); kA1 = min(59, max(0, kA1));
        kB0 = min(59, max(0, kB0)); kB1 = min(59, max(0, kB1));

        const float4* A0 = (const float4*)(s_ya + kA0 * 20);
        const float4* A1 = (const float4*)(s_ya + kA1 * 20);
        const float4* B0 = (const float4*)(s_yb + kB0 * 20);
        const float4* B1 = (const float4*)(s_yb + kB1 * 20);

        float xf[20];
#pragma unroll
        for (int r = 0; r < 5; r++) {
            float4 a0 = A0[r], a1 = A1[r], c0 = B0[r], c1 = B1[r];
            xf[4 * r + 0] = fmaxf(a0.x + a1.x + c0.x + c1.x, 0.f);
            xf[4 * r + 1] = fmaxf(a0.y + a1.y + c0.y + c1.y, 0.f);
            xf[4 * r + 2] = fmaxf(a0.z + a1.z + c0.z + c1.z, 0.f);
            xf[4 * r + 3] = fmaxf(a0.w + a1.w + c0.w + c1.w, 0.f);
        }

        int m = (mrow >> j) & 1;
        const float* wbase = s_wcm + m * 400;
        float acc = 0.f;
#pragma unroll
        for (int q = 0; q < 20; q++) {
            const float4* w4 = (const float4*)(wbase + q * 20);
            float h = s_bcomb[q];
#pragma unroll
            for (int r = 0; r < 5; r++) {
                float4 w = w4[r];
                h = fmaf(w.x, xf[4 * r + 0], h);
                h = fmaf(w.y, xf[4 * r + 1], h);
                h = fmaf(w.z, xf[4 * r + 2], h);
                h = fmaf(w.w, xf[4 * r + 3], h);
            }
            acc = fmaf(s_wfin[q], fmaxf(h, 0.f), acc);
        }
        total += fmaxf(acc + s_bfin, 0.f);
        b++;
    }
    out[t] = total;
}

extern "C" void kernel_launch(void* const* d_in, const int* in_sizes, int n_in,
                              void* d_out, int out_size, void* d_ws, size_t ws_size,
                              hipStream_t stream) {
    const float* feat      = (const float*)d_in[0];
    const float* emb_phase = (const float*)d_in[1];
    const float* w_veh     = (const float*)d_in[2];
    const float* b_veh     = (const float*)d_in[3];
    const float* w_line    = (const float*)d_in[4];
    const float* b_line    = (const float*)d_in[5];
    const float* emb_const = (const float*)d_in[6];
    const float* w_feat    = (const float*)d_in[7];
    const float* b_feat    = (const float*)d_in[8];
    const float* w_const   = (const float*)d_in[9];
    const float* b_const   = (const float*)d_in[10];
    const float* w_comb    = (const float*)d_in[11];
    const float* b_comb    = (const float*)d_in[12];
    const float* w_final   = (const float*)d_in[13];
    const float* b_final   = (const float*)d_in[14];
    const int*   cmask     = (const int*)d_in[15];

    int B = in_sizes[0] / 16;           // 16384
    int threads = B * 8;
    int blocks = (threads + 255) / 256;
    frap_fused<<<blocks, 256, 0, stream>>>(feat, emb_phase, w_veh, b_veh,
                                           w_line, b_line, emb_const, w_feat,
                                           b_feat, w_const, b_const, w_comb,
                                           b_comb, w_final, b_final, cmask,
                                           (float*)d_out, B);
}